// Round 9
// baseline (596.552 us; speedup 1.0000x reference)
//
#include <hip/hip_runtime.h>
#include <hip/hip_bf16.h>

// Problem constants
constexpr int Bn  = 128;   // batch
constexpr int Ln  = 200;   // sentences
constexpr int D2n = 1024;  // 2*SH
constexpr int G3n = 1536;  // 3*EH
constexpr int Tn  = 3;
constexpr int Nn  = 512;   // A (attention dim) == d_proj cols
constexpr int Kn  = 1024;  // d_proj K

typedef unsigned short ushort;
typedef float f32x4 __attribute__((ext_vector_type(4)));
typedef __bf16 bf16x8 __attribute__((ext_vector_type(8)));

__device__ __forceinline__ ushort f2bf(float f) {   // RNE float->bf16
  unsigned u = __float_as_uint(f);
  unsigned r = (u + 0x7fffu + ((u >> 16) & 1u)) >> 16;
  return (ushort)r;
}
__device__ __forceinline__ float bf2f(ushort h) {
  return __uint_as_float(((unsigned)h) << 16);
}

__device__ __forceinline__ void gld_lds16(const ushort* g, ushort* l) {
  __builtin_amdgcn_global_load_lds(
      (const __attribute__((address_space(1))) unsigned int*)g,
      (__attribute__((address_space(3))) unsigned int*)l, 16, 0, 0);
}

// fast tanh: (e^{2x}-1)/(e^{2x}+1), clamped; err ~1e-6, << bf16-split noise
__device__ __forceinline__ float ftanh(float x) {
  float cx = fminf(fmaxf(x, -15.f), 15.f);
  float e  = __expf(2.f * cx);
  return (e - 1.f) * __builtin_amdgcn_rcpf(e + 1.f);
}

// ---------------------------------------------------------------------------
// split fp32 -> hi/lo bf16 (wd, sent)
__global__ void k_split(const float* __restrict__ W, ushort* __restrict__ hi,
                        ushort* __restrict__ lo) {
  int i = blockIdx.x * 256 + threadIdx.x;        // float4 index
  float4 v = ((const float4*)W)[i];
  ushort4 h, l;
  h.x = f2bf(v.x); l.x = f2bf(v.x - bf2f(h.x));
  h.y = f2bf(v.y); l.y = f2bf(v.y - bf2f(h.y));
  h.z = f2bf(v.z); l.z = f2bf(v.z - bf2f(h.z));
  h.w = f2bf(v.w); l.w = f2bf(v.w - bf2f(h.w));
  ((ushort4*)hi)[i] = h;
  ((ushort4*)lo)[i] = l;
}

// combined weight split: w_ih (393216 f4) + w_hh (196608 f4)
__global__ void k_split3(const float* __restrict__ w_ih, const float* __restrict__ w_hh,
                         ushort* __restrict__ WihH, ushort* __restrict__ WihL,
                         ushort* __restrict__ WhhH, ushort* __restrict__ WhhL) {
  int i = blockIdx.x * 256 + threadIdx.x;        // 0..589823
  const float* src; ushort* hi; ushort* lo; int off;
  if (i < 393216) { src = w_ih; hi = WihH; lo = WihL; off = i; }
  else            { src = w_hh; hi = WhhH; lo = WhhL; off = i - 393216; }
  float4 v = ((const float4*)src)[off];
  ushort4 h, l;
  h.x = f2bf(v.x); l.x = f2bf(v.x - bf2f(h.x));
  h.y = f2bf(v.y); l.y = f2bf(v.y - bf2f(h.y));
  h.z = f2bf(v.z); l.z = f2bf(v.z - bf2f(h.z));
  h.w = f2bf(v.w); l.w = f2bf(v.w - bf2f(h.w));
  ((ushort4*)hi)[off] = h;
  ((ushort4*)lo)[off] = l;
}

// ---------------------------------------------------------------------------
// 32x32 tiled transpose (R4-proven): out[c][r] = in[r][c]
__global__ void k_transp(const float* __restrict__ in, float* __restrict__ out,
                         int R, int C) {
  __shared__ float t[32][33];
  const int x = threadIdx.x, y = threadIdx.y;     // 32 x 8
  const int c0 = blockIdx.x * 32, r0 = blockIdx.y * 32;
  #pragma unroll
  for (int i = 0; i < 4; ++i)
    t[y + i * 8][x] = in[(size_t)(r0 + y + i * 8) * C + c0 + x];
  __syncthreads();
  #pragma unroll
  for (int i = 0; i < 4; ++i)
    out[(size_t)(c0 + y + i * 8) * R + r0 + x] = t[x][y + i * 8];
}

// ---------------------------------------------------------------------------
// h0 = tanh(last_back @ h0_w^T + h0_b), gather fused, writes fp32 + hi/lo split
__launch_bounds__(256)
__global__ void k_h0(const float* __restrict__ sent, const float* __restrict__ W,
                     const float* __restrict__ bias, float* __restrict__ out,
                     ushort* __restrict__ outh, ushort* __restrict__ outl) {
  __shared__ float s[16 * 512];
  const int b0 = blockIdx.y * 16;
  const int jl = threadIdx.x & 63;
  const int j  = blockIdx.x * 64 + jl;
  const int bg = (threadIdx.x >> 6) * 4;

  for (int i = threadIdx.x; i < 2048; i += 256) {   // 16 rows x 128 float4
    int r = i >> 7, c = i & 127;
    ((float4*)s)[i] = *(const float4*)(sent + (size_t)(b0 + r) * (Ln * D2n) + 512 + c * 4);
  }
  __syncthreads();

  const float4* w4 = (const float4*)(W + (size_t)j * 512);
  const float4* r0 = (const float4*)(s + (size_t)(bg + 0) * 512);
  const float4* r1 = (const float4*)(s + (size_t)(bg + 1) * 512);
  const float4* r2 = (const float4*)(s + (size_t)(bg + 2) * 512);
  const float4* r3 = (const float4*)(s + (size_t)(bg + 3) * 512);

  float acc0 = 0.f, acc1 = 0.f, acc2 = 0.f, acc3 = 0.f;
  #pragma unroll 4
  for (int k4 = 0; k4 < 128; ++k4) {
    float4 wv = w4[k4];
    float4 a;
    a = r0[k4]; acc0 += wv.x*a.x + wv.y*a.y + wv.z*a.z + wv.w*a.w;
    a = r1[k4]; acc1 += wv.x*a.x + wv.y*a.y + wv.z*a.z + wv.w*a.w;
    a = r2[k4]; acc2 += wv.x*a.x + wv.y*a.y + wv.z*a.z + wv.w*a.w;
    a = r3[k4]; acc3 += wv.x*a.x + wv.y*a.y + wv.z*a.z + wv.w*a.w;
  }
  float bb = bias[j];
  float accs[4] = {acc0, acc1, acc2, acc3};
  #pragma unroll
  for (int i = 0; i < 4; ++i) {
    float v = tanhf(accs[i] + bb);
    size_t o = (size_t)(b0 + bg + i) * 512 + j;
    out[o] = v;
    ushort hv = f2bf(v);
    outh[o] = hv;
    outl[o] = f2bf(v - bf2f(hv));
  }
}

// ---------------------------------------------------------------------------
// 128x128-tile split-bf16 MFMA (proven: 0 bank conflicts) -- dproj only now.
template<int KK>
__device__ __forceinline__ void mfma_tile128(
    const ushort* __restrict__ Ah, const ushort* __restrict__ Al,
    const ushort* __restrict__ Bh, const ushort* __restrict__ Bl,
    const float* __restrict__ bias, float* __restrict__ C, int ldc,
    int m0, int n0) {
  __shared__ __align__(16) ushort sAh[128 * 32];
  __shared__ __align__(16) ushort sAl[128 * 32];
  __shared__ __align__(16) ushort sBh[128 * 32];
  __shared__ __align__(16) ushort sBl[128 * 32];

  const int tid  = threadIdx.x;
  const int wave = tid >> 6, lane = tid & 63;
  const int wy = (wave >> 1) * 64, wx = (wave & 1) * 64;
  const int lm = lane & 15, lq = lane >> 4;
  const int fs = (lq ^ ((lm >> 1) & 3)) * 8;     // swizzled 16B slot

  const int S0 = (wave * 2 + 0) * 64 + lane;
  const int S1 = (wave * 2 + 1) * 64 + lane;
  const int r0 = S0 >> 2, r1 = S1 >> 2;
  const int c0 = ((S0 & 3) ^ ((r0 >> 1) & 3)) * 8;
  const int c1 = ((S1 & 3) ^ ((r1 >> 1) & 3)) * 8;
  const ushort* pAh0 = Ah + (size_t)(m0 + r0) * KK + c0;
  const ushort* pAh1 = Ah + (size_t)(m0 + r1) * KK + c1;
  const ushort* pAl0 = Al + (size_t)(m0 + r0) * KK + c0;
  const ushort* pAl1 = Al + (size_t)(m0 + r1) * KK + c1;
  const ushort* pBh0 = Bh + (size_t)(n0 + r0) * KK + c0;
  const ushort* pBh1 = Bh + (size_t)(n0 + r1) * KK + c1;
  const ushort* pBl0 = Bl + (size_t)(n0 + r0) * KK + c0;
  const ushort* pBl1 = Bl + (size_t)(n0 + r1) * KK + c1;
  ushort* dA0 = &sAh[S0 * 8]; ushort* dA1 = &sAh[S1 * 8];
  ushort* dL0 = &sAl[S0 * 8]; ushort* dL1 = &sAl[S1 * 8];
  ushort* dB0 = &sBh[S0 * 8]; ushort* dB1 = &sBh[S1 * 8];
  ushort* dC0 = &sBl[S0 * 8]; ushort* dC1 = &sBl[S1 * 8];

  f32x4 acc[4][4] = {};

  for (int ks = 0; ks < KK / 32; ++ks) {
    const int ko = ks * 32;
    gld_lds16(pAh0 + ko, dA0); gld_lds16(pAh1 + ko, dA1);
    gld_lds16(pAl0 + ko, dL0); gld_lds16(pAl1 + ko, dL1);
    gld_lds16(pBh0 + ko, dB0); gld_lds16(pBh1 + ko, dB1);
    gld_lds16(pBl0 + ko, dC0); gld_lds16(pBl1 + ko, dC1);
    __syncthreads();

    bf16x8 ah[4], al[4], bh[4], bl[4];
    #pragma unroll
    for (int mi = 0; mi < 4; ++mi) {
      const int o = (wy + mi * 16 + lm) * 32 + fs;
      ah[mi] = *(const bf16x8*)&sAh[o];
      al[mi] = *(const bf16x8*)&sAl[o];
    }
    #pragma unroll
    for (int ni = 0; ni < 4; ++ni) {
      const int o = (wx + ni * 16 + lm) * 32 + fs;
      bh[ni] = *(const bf16x8*)&sBh[o];
      bl[ni] = *(const bf16x8*)&sBl[o];
    }
    #pragma unroll
    for (int mi = 0; mi < 4; ++mi)
      #pragma unroll
      for (int ni = 0; ni < 4; ++ni) {
        acc[mi][ni] = __builtin_amdgcn_mfma_f32_16x16x32_bf16(ah[mi], bh[ni], acc[mi][ni], 0, 0, 0);
        acc[mi][ni] = __builtin_amdgcn_mfma_f32_16x16x32_bf16(ah[mi], bl[ni], acc[mi][ni], 0, 0, 0);
        acc[mi][ni] = __builtin_amdgcn_mfma_f32_16x16x32_bf16(al[mi], bh[ni], acc[mi][ni], 0, 0, 0);
      }
    __syncthreads();
  }

  #pragma unroll
  for (int ni = 0; ni < 4; ++ni) {
    int col = n0 + wx + ni * 16 + lm;
    float bb = bias[col];
    #pragma unroll
    for (int mi = 0; mi < 4; ++mi) {
      int rbase = m0 + wy + mi * 16 + lq * 4;
      #pragma unroll
      for (int r = 0; r < 4; ++r)
        C[(size_t)(rbase + r) * ldc + col] = acc[mi][ni][r] + bb;
    }
  }
}

__launch_bounds__(256)
__global__ void k_dproj_mfma(const ushort* __restrict__ Ahi, const ushort* __restrict__ Alo,
                             const ushort* __restrict__ Whi, const ushort* __restrict__ Wlo,
                             const float* __restrict__ bias, float* __restrict__ C) {
  const int bid = blockIdx.x;
  mfma_tile128<1024>(Ahi, Alo, Whi, Wlo, bias, C, Nn, (bid % 200) * 128, (bid / 200) * 128);
}

// ---------------------------------------------------------------------------
// Fused GRU gates + pointwise, v3: R8 geometry (grid 64 = 2 b-halves x 32
// j-tiles, BK=64 via two swizzled 32-col sub-tiles) + DOUBLE-BUFFERED LDS
// with the R1-v3-proven 1-barrier pipeline: stage(s+1) issued before
// compute(s); each thread drains its own gld (vmcnt 0) before next barrier.
__launch_bounds__(256)
__global__ void k_gates(const ushort* __restrict__ sxh, const ushort* __restrict__ sxl,
                        const float* __restrict__ hOld,
                        const ushort* __restrict__ hh, const ushort* __restrict__ hl,
                        const ushort* __restrict__ WihH, const ushort* __restrict__ WihL,
                        const ushort* __restrict__ WhhH, const ushort* __restrict__ WhhL,
                        const float* __restrict__ b_ih, const float* __restrict__ b_hh,
                        float* __restrict__ hNew, ushort* __restrict__ hhN,
                        ushort* __restrict__ hlN) {
  __shared__ __align__(16) ushort sAh[2][2][64 * 32];
  __shared__ __align__(16) ushort sAl[2][2][64 * 32];
  __shared__ __align__(16) ushort sWh[2][2][48 * 32];  // 3 gates x 16 j rows
  __shared__ __align__(16) ushort sWl[2][2][48 * 32];

  const int bb  = blockIdx.x >> 5;                // batch half
  const int j0  = (blockIdx.x & 31) * 16;         // j tile
  const int rb0 = bb * 64;
  const int tid = threadIdx.x, wave = tid >> 6, lane = tid & 63;
  const int wy = wave * 16;                       // wave's 16 b-rows
  const int lm = lane & 15, lq = lane >> 4;
  const int fs = (lq ^ ((lm >> 1) & 3)) * 8;

  const int rA = tid >> 2;                        // local row 0..63
  const int cA = ((tid & 3) ^ ((rA >> 1) & 3)) * 8;
  const bool wOn = tid < 192;                     // wave-uniform
  const int gw = (rA >> 4) * 512 + j0 + (rA & 15);

  const ushort* sxh_r = sxh + (size_t)(rb0 + rA) * 1024 + cA;
  const ushort* sxl_r = sxl + (size_t)(rb0 + rA) * 1024 + cA;
  const ushort* hh_r  = hh  + (size_t)(rb0 + rA) * 512  + cA;
  const ushort* hl_r  = hl  + (size_t)(rb0 + rA) * 512  + cA;
  const ushort* wih_h = WihH + (size_t)gw * 1024 + cA;
  const ushort* wih_l = WihL + (size_t)gw * 1024 + cA;
  const ushort* whh_h = WhhH + (size_t)gw * 512 + cA;
  const ushort* whh_l = WhhL + (size_t)gw * 512 + cA;

  auto stage = [&](int s, int buf) {
    if (s < 16) {
      const int ko = s * 64;
      #pragma unroll
      for (int kk = 0; kk < 2; ++kk) {
        gld_lds16(sxh_r + ko + kk * 32, &sAh[buf][kk][tid * 8]);
        gld_lds16(sxl_r + ko + kk * 32, &sAl[buf][kk][tid * 8]);
        if (wOn) {
          gld_lds16(wih_h + ko + kk * 32, &sWh[buf][kk][tid * 8]);
          gld_lds16(wih_l + ko + kk * 32, &sWl[buf][kk][tid * 8]);
        }
      }
    } else {
      const int ko = (s - 16) * 64;
      #pragma unroll
      for (int kk = 0; kk < 2; ++kk) {
        gld_lds16(hh_r + ko + kk * 32, &sAh[buf][kk][tid * 8]);
        gld_lds16(hl_r + ko + kk * 32, &sAl[buf][kk][tid * 8]);
        if (wOn) {
          gld_lds16(whh_h + ko + kk * 32, &sWh[buf][kk][tid * 8]);
          gld_lds16(whh_l + ko + kk * 32, &sWl[buf][kk][tid * 8]);
        }
      }
    }
  };

  f32x4 ax[3] = {};
  f32x4 ag[3] = {};

  auto compute = [&](int cur, f32x4 (&acc)[3]) {
    const int oA = (wy + lm) * 32 + fs;
    #pragma unroll
    for (int kk = 0; kk < 2; ++kk) {
      bf16x8 fah = *(const bf16x8*)&sAh[cur][kk][oA];
      bf16x8 fal = *(const bf16x8*)&sAl[cur][kk][oA];
      #pragma unroll
      for (int g = 0; g < 3; ++g) {
        const int oW = (g * 16 + lm) * 32 + fs;
        bf16x8 fbh = *(const bf16x8*)&sWh[cur][kk][oW];
        bf16x8 fbl = *(const bf16x8*)&sWl[cur][kk][oW];
        acc[g] = __builtin_amdgcn_mfma_f32_16x16x32_bf16(fah, fbh, acc[g], 0, 0, 0);
        acc[g] = __builtin_amdgcn_mfma_f32_16x16x32_bf16(fah, fbl, acc[g], 0, 0, 0);
        acc[g] = __builtin_amdgcn_mfma_f32_16x16x32_bf16(fal, fbh, acc[g], 0, 0, 0);
      }
    }
  };

  // prologue: stage step 0 into buffer 0, drain own loads
  stage(0, 0);
  asm volatile("s_waitcnt vmcnt(0)" ::: "memory");

  for (int s = 0; s < 24; ++s) {
    const int cur = s & 1, nxt = cur ^ 1;
    __syncthreads();                   // buf[cur] fully staged (all threads drained)
    if (s + 1 < 24) stage(s + 1, nxt); // prefetch flies under the MFMAs below
    if (s < 16) compute(cur, ax); else compute(cur, ag);
    if (s + 1 < 24)
      asm volatile("s_waitcnt vmcnt(0)" ::: "memory");  // own prefetch landed
  }

  // ---- epilogue: GRU pointwise, write h fp32 + hi/lo split
  const int j = j0 + lm;
  const float bir = b_ih[j], biz = b_ih[512 + j], bin = b_ih[1024 + j];
  const float bhr = b_hh[j], bhz = b_hh[512 + j], bhn = b_hh[1024 + j];
  #pragma unroll
  for (int rr = 0; rr < 4; ++rr) {
    const int b = rb0 + wy + lq * 4 + rr;
    float xr = ax[0][rr] + bir, hr = ag[0][rr] + bhr;
    float xz = ax[1][rr] + biz, hz = ag[1][rr] + bhz;
    float xn = ax[2][rr] + bin, hn = ag[2][rr] + bhn;
    float r = 1.f / (1.f + expf(-(xr + hr)));
    float z = 1.f / (1.f + expf(-(xz + hz)));
    float n = tanhf(xn + r * hn);
    float hv = hOld[(size_t)b * 512 + j];
    float hw = (1.f - z) * n + z * hv;
    hNew[(size_t)b * 512 + j] = hw;
    ushort hbf = f2bf(hw);
    hhN[(size_t)b * 512 + j] = hbf;
    hlN[(size_t)b * 512 + j] = f2bf(hw - bf2f(hbf));
  }
}

// ---------------------------------------------------------------------------
// Fused q + score + argmax + select: one block per batch b.
// q[b,:] computed in-block (fp32, transposed wq => coalesced), kept in LDS;
// then 4 waves x 50 rows score; wave0 argmax; gather+split s_row.
__launch_bounds__(256)
__global__ void k_score_argmax(const float* __restrict__ dproj, const float* __restrict__ h,
                               const float* __restrict__ wqT, const float* __restrict__ bq,
                               const float* __restrict__ wsv, const float* __restrict__ bsv,
                               const float* __restrict__ sent,
                               ushort* __restrict__ s_rowh, ushort* __restrict__ s_rowl,
                               int* __restrict__ mask, float* __restrict__ outScores,
                               float* __restrict__ outSel, int t) {
  const int b = blockIdx.x;
  const int tid = threadIdx.x, lane = tid & 63, wv = tid >> 6;
  __shared__ float shb[512];
  __shared__ float sq[512];
  __shared__ float ssc[Ln];
  __shared__ int s_idx;

  if (tid < 128)
    ((float4*)shb)[tid] = ((const float4*)(h + (size_t)b * 512))[tid];
  __syncthreads();

  // q[b][2*tid..2*tid+1] = sum_k h[k] * wqT[k][...]  (coalesced float2)
  float qx = 0.f, qy = 0.f;
  #pragma unroll 8
  for (int k = 0; k < 512; ++k) {
    float hk = shb[k];
    float2 w = ((const float2*)(wqT + (size_t)k * 512))[tid];
    qx += hk * w.x; qy += hk * w.y;
  }
  sq[tid * 2]     = qx + bq[tid * 2];
  sq[tid * 2 + 1] = qy + bq[tid * 2 + 1];
  __syncthreads();

  const float4* q4  = (const float4*)sq;
  const float4* ws4 = (const float4*)wsv;
  const float4 qq0 = q4[lane],  qq1 = q4[lane + 64];
  const float4 wv0 = ws4[lane], wv1 = ws4[lane + 64];
  const float bs0 = bsv[0];

  for (int l = wv; l < Ln; l += 4) {
    const float4* dp4 = (const float4*)(dproj + ((size_t)b * Ln + l) * Nn);
    float4 d0 = dp4[lane], d1 = dp4[lane + 64];
    float sum = ftanh(qq0.x + d0.x) * wv0.x + ftanh(qq0.y + d0.y) * wv0.y
              + ftanh(qq0.z + d0.z) * wv0.z + ftanh(qq0.w + d0.w) * wv0.w
              + ftanh(qq1.x + d1.x) * wv1.x + ftanh(qq1.y + d1.y) * wv1.y
              + ftanh(qq1.z + d1.z) * wv1.z + ftanh(qq1.w + d1.w) * wv1.w;
    #pragma unroll
    for (int off = 32; off > 0; off >>= 1) sum += __shfl_xor(sum, off, 64);
    if (lane == 0) {
      float v = sum + bs0;
      if (mask[b * Ln + l]) v = -1000000.0f;
      ssc[l] = v;
      outScores[(size_t)b * (Tn * Ln) + t * Ln + l] = v;
    }
  }
  __syncthreads();

  if (tid < 64) {
    float best = -3.0e38f; int bi = 0;
    for (int l = tid; l < Ln; l += 64) {
      float v = ssc[l];
      if (v > best) { best = v; bi = l; }        // increasing l: > keeps first
    }
    #pragma unroll
    for (int off = 32; off > 0; off >>= 1) {
      float ov = __shfl_down(best, off, 64);
      int   oi = __shfl_down(bi,   off, 64);
      if (ov > best || (ov == best && oi < bi)) { best = ov; bi = oi; }
    }
    if (tid == 0) s_idx = bi;
  }
  __syncthreads();
  int idx = s_idx;
  const float* src = sent + ((size_t)b * Ln + idx) * D2n;
  int k = tid * 4;                               // 256 x 4 = 1024
  float4 v = *(const float4*)(src + k);
  ushort4 hvec, lvec;
  hvec.x = f2bf(v.x); lvec.x = f2bf(v.x - bf2f(hvec.x));
  hvec.y = f2bf(v.y); lvec.y = f2bf(v.y - bf2f(hvec.y));
  hvec.z = f2bf(v.z); lvec.z = f2bf(v.z - bf2f(hvec.z));
  hvec.w = f2bf(v.w); lvec.w = f2bf(v.w - bf2f(hvec.w));
  *(ushort4*)(s_rowh + (size_t)b * 1024 + k) = hvec;
  *(ushort4*)(s_rowl + (size_t)b * 1024 + k) = lvec;
  if (tid == 0) {
    mask[b * Ln + idx] = 1;
    outSel[(size_t)b * Tn + t] = (float)idx;
  }
}

// ---------------------------------------------------------------------------
extern "C" void kernel_launch(void* const* d_in, const int* in_sizes, int n_in,
                              void* d_out, int out_size, void* d_ws, size_t ws_size,
                              hipStream_t stream) {
  const float* sent = (const float*)d_in[0];
  const float* h0_w = (const float*)d_in[1];
  const float* h0_b = (const float*)d_in[2];
  const float* w_ih = (const float*)d_in[3];
  const float* w_hh = (const float*)d_in[4];
  const float* b_ih = (const float*)d_in[5];
  const float* b_hh = (const float*)d_in[6];
  const float* wq   = (const float*)d_in[7];
  const float* bq   = (const float*)d_in[8];
  const float* wd   = (const float*)d_in[9];
  const float* bd   = (const float*)d_in[10];
  const float* wsv  = (const float*)d_in[11];
  const float* bsv  = (const float*)d_in[12];

  // ---- workspace (base region smaller than R8's proven 161.3 MB) ----
  float* wsf     = (float*)d_ws;
  float* d_proj  = wsf;                       // 13,107,200 f
  float* hA      = d_proj + 13107200;         // 65,536 f
  float* hB      = hA + 65536;                // 65,536 f
  int*   mask    = (int*)(hB + 65536);        // 25,600 int
  ushort* Whi    = (ushort*)(mask + 25600);   // 524,288 us
  ushort* Wlo    = Whi + 524288;              // 524,288 us
  ushort* hhA    = Wlo + 524288;              // 65,536 us
  ushort* hlA    = hhA + 65536;
  ushort* hhB    = hlA + 65536;
  ushort* hlB    = hhB + 65536;
  ushort* s_rowh = hlB + 65536;               // 131,072 us
  ushort* s_rowl = s_rowh + 131072;           // 131,072 us
  ushort* Ahi    = s_rowl + 131072;           // 26,214,400 us
  ushort* Alo    = Ahi + 26214400;            // 26,214,400 us

  // ---- aliased into Ahi (dead after k_dproj_mfma); writes stream-after dproj
  ushort* WihH   = Ahi;                       // 1,572,864 us
  ushort* WihL   = WihH + 1572864;            // 1,572,864
  ushort* WhhH   = WihL + 1572864;            // 786,432
  ushort* WhhL   = WhhH + 786432;             // 786,432
  float*  wqT    = (float*)(WhhL + 786432);   // 262,144 f (1 MB); sum 10.4MB << 52.4MB

  float* outScores = (float*)d_out;                       // (B, T, L) fp32
  float* outSel    = outScores + (size_t)Bn * Tn * Ln;    // (B, T) fp32

  hipMemsetAsync(mask, 0, 25600 * sizeof(int), stream);
  hipMemsetAsync(s_rowh, 0, 2 * 131072 * sizeof(ushort), stream);  // s_prev(0)=0

  // ---- preamble ----
  k_h0<<<dim3(8, 8), 256, 0, stream>>>(sent, h0_w, h0_b, hA, hhA, hlA);
  k_split<<<512,   256, 0, stream>>>(wd, Whi, Wlo);
  k_split<<<25600, 256, 0, stream>>>(sent, Ahi, Alo);
  k_dproj_mfma<<<800, 256, 0, stream>>>(Ahi, Alo, Whi, Wlo, bd, d_proj);
  k_split3<<<2304, 256, 0, stream>>>(w_ih, w_hh, WihH, WihL, WhhH, WhhL);
  k_transp<<<dim3(16, 16), dim3(32, 8), 0, stream>>>(wq, wqT, 512, 512);

  float* hc = hA;  ushort* hhc = hhA; ushort* hlc = hlA;
  float* hn = hB;  ushort* hhn = hhB; ushort* hln = hlB;
  for (int t = 0; t < Tn; ++t) {
    k_gates<<<64, 256, 0, stream>>>(s_rowh, s_rowl, hc, hhc, hlc,
                                    WihH, WihL, WhhH, WhhL, b_ih, b_hh,
                                    hn, hhn, hln);
    k_score_argmax<<<128, 256, 0, stream>>>(d_proj, hn, wqT, bq, wsv, bsv, sent,
                                            s_rowh, s_rowl, mask,
                                            outScores, outSel, t);
    float* tf = hc; hc = hn; hn = tf;
    ushort* t1 = hhc; hhc = hhn; hhn = t1;
    ushort* t2 = hlc; hlc = hln; hln = t2;
  }
}